// Round 10
// baseline (3937.530 us; speedup 1.0000x reference)
//
#include <hip/hip_runtime.h>
#include <cstdint>
#include <cstddef>

#define BB 512   // batch
#define TT 512   // seq len
#define HH 100   // hidden
#define G4 400   // 4*H

// ---------------------------------------------------------------------------
// Recurrent kernel: full 512 steps of one layer in one launch.
// grid = 256 blocks x 832 threads (13 waves), 1 block/CU.
// Thread (u = tid>>3, s = tid&7): unit u (active u<100), k-split s.
// Holds w[4][16] = Whh[{i,f,g,o}_u][16s .. 16s+15] (zero-guarded past k=99)
// = 64 VGPRs; k padded to 128. Per step: 8 broadcast ds_read_b128 of
// h[window s] (2 chunks of 4) + 128 FMA -> 3-stage halving butterfly
// (7 shfl) leaves combo (gate = s>>1, elem = s&1) on lane s -> lane-parallel
// activation -> xor(4) pairs i<->g, f<->o; xor(2) ships i*g to the f-lane,
// which owns c/h. One __syncthreads per step.
// LDS traffic: 13 waves x 8 b128 = 104/step (vs ~180 in rounds 3-9 whose
// ~2200cy LDS floor explained the 660-820us plateau regardless of weight
// residency). h layout [buf][window][kk*2+e] with 36-float window stride:
// window bases hit disjoint bank quads (4*s pattern) -> conflict-free.
// Register budget ~108 — fits the ~120 the allocator actually gives.
// ---------------------------------------------------------------------------
template<bool IS_L0, bool WRITE_DROP>
__global__ __launch_bounds__(832, 1)
void rec_kernel(const float* __restrict__ x,       // [B][T] (layer0 input, IN=1)
                const float* __restrict__ xc,      // [T][B][400] (layers>0)
                const float* __restrict__ Whh_l,   // [400][100]
                const float* __restrict__ Wih0,    // [400] (layer0)
                const float* __restrict__ bih_l,   // [400] (layer0)
                const float* __restrict__ bhh_l,   // [400] (layer0)
                const float* __restrict__ dmask_l, // [B][T][100] (if WRITE_DROP)
                float* __restrict__ hdrop,         // [T][B][100] (if WRITE_DROP)
                float* __restrict__ st_h,          // [B][100]
                float* __restrict__ st_c)          // [B][100]
{
    __shared__ float hbuf[2][8][36];   // [buf][k-window][kk*2+e], 2304 B

    const int tid = threadIdx.x;
    const int u   = tid >> 3;                  // 0..103 (unit)
    const int s   = tid & 7;                   // k-split lane
    const bool uok = (u < HH);
    const int uc  = uok ? u : (HH - 1);
    const int g   = s >> 1;                    // final gate combo of this lane
    const int e   = s & 1;                     // final elem combo of this lane
    const int row = g * HH + uc;               // gate-row for gin prefetch
    const int b   = blockIdx.x * 2 + e;
    const bool hOwn = (g == 1) && uok;         // f-lanes own c/h
    const bool isg  = (g == 2);                // tanh lane

    // --- weights: all 4 gates of unit u over k-window [16s, 16s+16) ---
    float w[4][16];
    {
        const int k0 = 16 * s;
        #pragma unroll
        for (int gg = 0; gg < 4; ++gg) {
            const float* wrow = Whh_l + (size_t)(gg * HH + uc) * HH;
            #pragma unroll
            for (int q = 0; q < 4; ++q) {
                const int gk = k0 + 4 * q;
                if (gk + 3 < HH) {   // aligned: row*100 and 16s+4q are mult of 4
                    const float4 v = *(const float4*)(wrow + gk);
                    w[gg][4*q+0] = v.x; w[gg][4*q+1] = v.y;
                    w[gg][4*q+2] = v.z; w[gg][4*q+3] = v.w;
                } else {
                    #pragma unroll
                    for (int i = 0; i < 4; ++i)
                        w[gg][4*q+i] = (gk + i < HH) ? wrow[gk + i] : 0.f;
                }
            }
        }
    }

    float wx = 0.f, bs = 0.f;
    if (IS_L0) { wx = Wih0[row]; bs = bih_l[row] + bhh_l[row]; }

    // zero both h buffers (incl. padding)
    for (int i = tid; i < 2 * 8 * 36; i += 832) ((float*)hbuf)[i] = 0.f;

    float c2 = 0.f, hlast = 0.f;
    __syncthreads();

    // --- prefetch t = 0 ---
    const float* pxc = xc ? (xc + (size_t)b * G4 + row) : nullptr;
    const float* pdm = dmask_l ? (dmask_l + (size_t)b * TT * HH + uc) : nullptr;
    const float* px  = x ? (x + (size_t)b * TT) : nullptr;
    float gin = 0.f, xv = 0.f, mk = 0.f;
    if (IS_L0) xv = px[0];
    else       gin = pxc[0];
    if (WRITE_DROP && hOwn) mk = pdm[0];

    int cur = 0;
    for (int t = 0; t < TT; ++t) {
        const bool last = (t + 1 == TT);
        const float* nxc = (!IS_L0 && !last) ? pxc + (size_t)BB * G4 : pxc;
        const float* ndm = (WRITE_DROP && hOwn && !last) ? pdm + HH : pdm;
        const float* npx = (IS_L0 && !last) ? px + 1 : px;

        // prefetch t+1
        float nxv = 0.f, ngin = 0.f, nmk = 0.f;
        if (IS_L0) nxv = npx[0];
        else       ngin = nxc[0];
        if (WRITE_DROP && hOwn) nmk = ndm[0];

        if (IS_L0) gin = fmaf(xv, wx, bs);

        // --- dot: 8 b128 broadcast reads (2 chunks of 4) + 128 FMA ---
        float acc[4][2];
        #pragma unroll
        for (int gg = 0; gg < 4; ++gg) { acc[gg][0] = 0.f; acc[gg][1] = 0.f; }
        {
            const float4* hp = (const float4*)&hbuf[cur][s][0];
            {
                const float4 h0 = hp[0], h1 = hp[1], h2 = hp[2], h3 = hp[3];
                #pragma unroll
                for (int gg = 0; gg < 4; ++gg) {
                    acc[gg][0] = fmaf(w[gg][0], h0.x, acc[gg][0]);
                    acc[gg][1] = fmaf(w[gg][0], h0.y, acc[gg][1]);
                    acc[gg][0] = fmaf(w[gg][1], h0.z, acc[gg][0]);
                    acc[gg][1] = fmaf(w[gg][1], h0.w, acc[gg][1]);
                    acc[gg][0] = fmaf(w[gg][2], h1.x, acc[gg][0]);
                    acc[gg][1] = fmaf(w[gg][2], h1.y, acc[gg][1]);
                    acc[gg][0] = fmaf(w[gg][3], h1.z, acc[gg][0]);
                    acc[gg][1] = fmaf(w[gg][3], h1.w, acc[gg][1]);
                    acc[gg][0] = fmaf(w[gg][4], h2.x, acc[gg][0]);
                    acc[gg][1] = fmaf(w[gg][4], h2.y, acc[gg][1]);
                    acc[gg][0] = fmaf(w[gg][5], h2.z, acc[gg][0]);
                    acc[gg][1] = fmaf(w[gg][5], h2.w, acc[gg][1]);
                    acc[gg][0] = fmaf(w[gg][6], h3.x, acc[gg][0]);
                    acc[gg][1] = fmaf(w[gg][6], h3.y, acc[gg][1]);
                    acc[gg][0] = fmaf(w[gg][7], h3.z, acc[gg][0]);
                    acc[gg][1] = fmaf(w[gg][7], h3.w, acc[gg][1]);
                }
            }
            {
                const float4 h0 = hp[4], h1 = hp[5], h2 = hp[6], h3 = hp[7];
                #pragma unroll
                for (int gg = 0; gg < 4; ++gg) {
                    acc[gg][0] = fmaf(w[gg][ 8], h0.x, acc[gg][0]);
                    acc[gg][1] = fmaf(w[gg][ 8], h0.y, acc[gg][1]);
                    acc[gg][0] = fmaf(w[gg][ 9], h0.z, acc[gg][0]);
                    acc[gg][1] = fmaf(w[gg][ 9], h0.w, acc[gg][1]);
                    acc[gg][0] = fmaf(w[gg][10], h1.x, acc[gg][0]);
                    acc[gg][1] = fmaf(w[gg][10], h1.y, acc[gg][1]);
                    acc[gg][0] = fmaf(w[gg][11], h1.z, acc[gg][0]);
                    acc[gg][1] = fmaf(w[gg][11], h1.w, acc[gg][1]);
                    acc[gg][0] = fmaf(w[gg][12], h2.x, acc[gg][0]);
                    acc[gg][1] = fmaf(w[gg][12], h2.y, acc[gg][1]);
                    acc[gg][0] = fmaf(w[gg][13], h2.z, acc[gg][0]);
                    acc[gg][1] = fmaf(w[gg][13], h2.w, acc[gg][1]);
                    acc[gg][0] = fmaf(w[gg][14], h3.x, acc[gg][0]);
                    acc[gg][1] = fmaf(w[gg][14], h3.y, acc[gg][1]);
                    acc[gg][0] = fmaf(w[gg][15], h3.z, acc[gg][0]);
                    acc[gg][1] = fmaf(w[gg][15], h3.w, acc[gg][1]);
                }
            }
        }

        // --- 3-stage halving butterfly over the 8 k-split lanes ---
        // stage 1 (xor 1): keep elem e
        float r1_0, r1_1, r1_2, r1_3;
        {
            float m0 = e ? acc[0][1] : acc[0][0], o0 = e ? acc[0][0] : acc[0][1];
            float m1 = e ? acc[1][1] : acc[1][0], o1 = e ? acc[1][0] : acc[1][1];
            float m2 = e ? acc[2][1] : acc[2][0], o2 = e ? acc[2][0] : acc[2][1];
            float m3 = e ? acc[3][1] : acc[3][0], o3 = e ? acc[3][0] : acc[3][1];
            r1_0 = m0 + __shfl_xor(o0, 1);
            r1_1 = m1 + __shfl_xor(o1, 1);
            r1_2 = m2 + __shfl_xor(o2, 1);
            r1_3 = m3 + __shfl_xor(o3, 1);
        }
        // stage 2 (xor 2): keep gate-bit0 == (s>>1)&1
        const bool gb0 = ((s >> 1) & 1) != 0;
        float r2_0 = gb0 ? r1_1 : r1_0, r2_0o = gb0 ? r1_0 : r1_1;
        float r2_1 = gb0 ? r1_3 : r1_2, r2_1o = gb0 ? r1_2 : r1_3;
        r2_0 += __shfl_xor(r2_0o, 2);
        r2_1 += __shfl_xor(r2_1o, 2);
        // stage 3 (xor 4): keep gate-bit1 == (s>>2)&1
        const bool gb1 = ((s >> 2) & 1) != 0;
        float m3v = gb1 ? r2_1 : r2_0, o3v = gb1 ? r2_0 : r2_1;
        const float tot = m3v + __shfl_xor(o3v, 4) + gin;

        // --- activation: gate s>>1 (2 = tanh, else sigmoid) ---
        const float E1  = __expf(isg ? (tot + tot) : (-tot));
        const float rr  = 1.f / (1.f + E1);
        const float act = isg ? fmaf(-2.f, rr, 1.f) : rr;

        // xor(4): i<->g, f<->o
        const float recvP = __shfl_xor(act, 4);
        // i-lanes form sig(i)*tanh(g); xor(2) ships it to the f-lane
        const float prod = act * recvP;
        const float ig   = __shfl_xor(prod, 2);

        const int nxt = cur ^ 1;
        if (hOwn) {   // f-lane: act = sig(f), recvP = sig(o)
            c2 = fmaf(act, c2, ig);
            const float Ec = __expf(c2 + c2);
            const float th = 1.f - 2.f / (Ec + 1.f);
            const float h  = recvP * th;
            hlast = h;
            hbuf[nxt][u >> 4][(u & 15) * 2 + e] = h;
            if (WRITE_DROP)
                hdrop[((size_t)t * BB + b) * HH + u] = h * mk * 2.f;
        }
        __syncthreads();
        cur = nxt;
        gin = ngin; xv = nxv; mk = nmk;
        pxc = nxc; pdm = ndm; px = npx;
    }

    if (hOwn) {
        st_h[(size_t)b * HH + u] = hlast;
        st_c[(size_t)b * HH + u] = c2;
    }
}

// ---------------------------------------------------------------------------
// Input-contribution GEMM for layers 1..3 (measured ~280us/launch):
// xc[m][n] = sum_k A[m][k]*W[n][k] + (bih[n]+bhh[n]), M=T*B=262144, N=400,K=100
// tile 128(M)x64(N), 256 threads, 8x4 microtile, LDS 80 KB -> 2 blocks/CU.
// ---------------------------------------------------------------------------
__global__ __launch_bounds__(256, 2)
void xc_gemm(const float* __restrict__ A,     // [M][100]
             const float* __restrict__ W,     // [400][100]
             const float* __restrict__ bih_l, // [400]
             const float* __restrict__ bhh_l, // [400]
             float* __restrict__ xc)          // [M][400]
{
    __shared__ float At[HH][132];
    __shared__ float Bt[HH][68];

    const int tid = threadIdx.x;
    const int n0  = blockIdx.x * 64;
    const size_t m0 = (size_t)blockIdx.y * 128;

    for (int s = tid; s < 128 * 25; s += 256) {
        const int r = s / 25, kq = s - r * 25;
        const float4 v = *(const float4*)&A[(m0 + r) * HH + kq * 4];
        At[kq * 4 + 0][r] = v.x; At[kq * 4 + 1][r] = v.y;
        At[kq * 4 + 2][r] = v.z; At[kq * 4 + 3][r] = v.w;
    }
    for (int s = tid; s < 64 * 25; s += 256) {
        const int r = s / 25, kq = s - r * 25;
        const int col = n0 + r;
        float4 v = {0.f, 0.f, 0.f, 0.f};
        if (col < G4) v = *(const float4*)&W[(size_t)col * HH + kq * 4];
        Bt[kq * 4 + 0][r] = v.x; Bt[kq * 4 + 1][r] = v.y;
        Bt[kq * 4 + 2][r] = v.z; Bt[kq * 4 + 3][r] = v.w;
    }
    __syncthreads();

    const int tx = tid & 15;   // col group: cols tx*4..+3
    const int ty = tid >> 4;   // row group: rows ty*8..+7
    float acc[8][4];
    #pragma unroll
    for (int i = 0; i < 8; ++i)
        #pragma unroll
        for (int jj = 0; jj < 4; ++jj) acc[i][jj] = 0.f;

    #pragma unroll 4
    for (int k = 0; k < HH; ++k) {
        const float4 a0 = *(const float4*)&At[k][ty * 8];
        const float4 a1 = *(const float4*)&At[k][ty * 8 + 4];
        const float4 bv = *(const float4*)&Bt[k][tx * 4];
        const float av[8] = {a0.x, a0.y, a0.z, a0.w, a1.x, a1.y, a1.z, a1.w};
        #pragma unroll
        for (int i = 0; i < 8; ++i) {
            acc[i][0] = fmaf(av[i], bv.x, acc[i][0]);
            acc[i][1] = fmaf(av[i], bv.y, acc[i][1]);
            acc[i][2] = fmaf(av[i], bv.z, acc[i][2]);
            acc[i][3] = fmaf(av[i], bv.w, acc[i][3]);
        }
    }

    const int col = n0 + tx * 4;
    if (col < G4) {
        const float4 u = *(const float4*)&bih_l[col];
        const float4 v = *(const float4*)&bhh_l[col];
        const float4 bias = {u.x + v.x, u.y + v.y, u.z + v.z, u.w + v.w};
        #pragma unroll
        for (int i = 0; i < 8; ++i) {
            const size_t r = m0 + ty * 8 + i;
            float4 o = {acc[i][0] + bias.x, acc[i][1] + bias.y,
                        acc[i][2] + bias.z, acc[i][3] + bias.w};
            *(float4*)&xc[r * G4 + col] = o;
        }
    }
}

// ---------------------------------------------------------------------------
__global__ __launch_bounds__(256)
void out_kernel(const float* __restrict__ st_h3,  // [B][100]
                const float* __restrict__ Wout,   // [100]
                const float* __restrict__ bout,   // [1]
                float* __restrict__ out)          // [B]
{
    const int b = blockIdx.x * 256 + threadIdx.x;
    if (b < BB) {
        float sum = bout[0];
        #pragma unroll 4
        for (int k = 0; k < HH; ++k)
            sum = fmaf(st_h3[(size_t)b * HH + k], Wout[k], sum);
        out[b] = sum;
    }
}

// ---------------------------------------------------------------------------
extern "C" void kernel_launch(void* const* d_in, const int* in_sizes, int n_in,
                              void* d_out, int out_size, void* d_ws, size_t ws_size,
                              hipStream_t stream)
{
    const float* x     = (const float*)d_in[0];  // [512][512][1]
    const float* Wih0  = (const float*)d_in[1];  // [400][1]
    const float* WihR  = (const float*)d_in[2];  // [3][400][100]
    const float* Whh   = (const float*)d_in[3];  // [4][400][100]
    const float* bih   = (const float*)d_in[4];  // [4][400]
    const float* bhh   = (const float*)d_in[5];  // [4][400]
    const float* Wout  = (const float*)d_in[6];  // [1][100]
    const float* bout  = (const float*)d_in[7];  // [1]
    const float* dmask = (const float*)d_in[8];  // [3][512][512][100]
    float* out = (float*)d_out;

    // ws layout (floats): ~526 MB of the 1200 MB workspace
    float* ws    = (float*)d_ws;
    float* xcb   = ws;                                  // T*B*400
    float* hdrop = xcb + (size_t)TT * BB * G4;          // T*B*100
    float* sth   = hdrop + (size_t)TT * BB * HH;        // 4*B*100
    float* stc   = sth + (size_t)4 * BB * HH;           // 4*B*100

    const dim3 rgrid(BB / 2), rblk(832);
    const dim3 ggrid(7, (TT * BB) / 128), gblk(256);

    // layer 0 (input dim 1 fused into rec)
    rec_kernel<true, true><<<rgrid, rblk, 0, stream>>>(
        x, nullptr, Whh, Wih0, bih, bhh, dmask,
        hdrop, sth, stc);
    // layers 1..3
    for (int l = 1; l < 4; ++l) {
        xc_gemm<<<ggrid, gblk, 0, stream>>>(
            hdrop, WihR + (size_t)(l - 1) * G4 * HH,
            bih + l * G4, bhh + l * G4, xcb);
        if (l < 3) {
            rec_kernel<false, true><<<rgrid, rblk, 0, stream>>>(
                nullptr, xcb, Whh + (size_t)l * G4 * HH,
                nullptr, nullptr, nullptr,
                dmask + (size_t)l * BB * TT * HH,
                hdrop, sth + (size_t)l * BB * HH, stc + (size_t)l * BB * HH);
        } else {
            rec_kernel<false, false><<<rgrid, rblk, 0, stream>>>(
                nullptr, xcb, Whh + (size_t)l * G4 * HH,
                nullptr, nullptr, nullptr,
                nullptr,
                nullptr, sth + (size_t)l * BB * HH, stc + (size_t)l * BB * HH);
        }
    }
    out_kernel<<<dim3(2), dim3(256), 0, stream>>>(sth + (size_t)3 * BB * HH, Wout, bout, out);
}